// Round 1
// baseline (91.832 us; speedup 1.0000x reference)
//
#include <hip/hip_runtime.h>

// Packed volume-render (NeRF ray compositing), one wave (64 lanes) per ray.
// ridx is sorted -> each ray is a contiguous sample segment. Each wave:
//   1. binary-searches ridx for its [start, end) segment
//   2. streams the segment in 64-sample chunks (coalesced loads)
//   3. wave-scan (shfl_up) of tau for the exclusive segmented cumsum
//   4. accumulates w, w*color, w*depth per lane; final wave reduce
//   5. lane 0 writes rgb (white-bg composite), depth, alpha, hit

__global__ __launch_bounds__(256) void render_kernel(
    const float* __restrict__ color,    // [N,3]
    const float* __restrict__ density,  // [N,1]
    const float* __restrict__ deltas,   // [N,1]
    const float* __restrict__ depths,   // [N,1]
    const int*   __restrict__ ridx,     // [N] sorted
    float*       __restrict__ out,      // rgb[3R] | depth[R] | alpha[R] | hit[R]
    int n_samples, int n_rays)
{
    const int wave = (int)((blockIdx.x * blockDim.x + threadIdx.x) >> 6);
    const int lane = (int)(threadIdx.x & 63);
    if (wave >= n_rays) return;
    const int r = wave;

    // lower_bound(ridx, r) on lane 0, lower_bound(ridx, r+1) on lanes 1..63.
    // All lanes run in lockstep; loads are broadcast (ridx region is L2/L3-hot).
    int target = r + (lane ? 1 : 0);
    int lo = 0, hi = n_samples;
    while (lo < hi) {
        int mid = (lo + hi) >> 1;
        if (ridx[mid] < target) lo = mid + 1; else hi = mid;
    }
    const int start = __shfl(lo, 0);
    const int end   = __shfl(lo, 1);

    float carry = 0.0f;                 // cumulative tau from previous chunks
    float aw = 0.0f, ar = 0.0f, ag = 0.0f, ab = 0.0f, ad = 0.0f;

    for (int base = start; base < end; base += 64) {
        const int i = base + lane;
        const bool valid = (i < end);
        float tau = 0.0f, c0 = 0.0f, c1 = 0.0f, c2 = 0.0f, dp = 0.0f;
        if (valid) {
            tau = density[i] * deltas[i];
            c0  = color[3 * i + 0];
            c1  = color[3 * i + 1];
            c2  = color[3 * i + 2];
            dp  = depths[i];
        }
        // inclusive wave scan of tau
        float x = tau;
        #pragma unroll
        for (int o = 1; o < 64; o <<= 1) {
            float y = __shfl_up(x, o);
            if (lane >= o) x += y;
        }
        const float excl = carry + (x - tau);       // exclusive segmented cumsum
        const float w = __expf(-excl) * (1.0f - __expf(-tau));
        aw += w;
        ar += w * c0;
        ag += w * c1;
        ab += w * c2;
        ad += w * dp;
        carry += __shfl(x, 63);                     // chunk total (invalid lanes add 0)
    }

    // wave reduction of the 5 accumulators
    #pragma unroll
    for (int o = 32; o > 0; o >>= 1) {
        aw += __shfl_down(aw, o);
        ar += __shfl_down(ar, o);
        ag += __shfl_down(ag, o);
        ab += __shfl_down(ab, o);
        ad += __shfl_down(ad, o);
    }

    if (lane == 0) {
        const float alpha = aw;
        out[3 * r + 0] = (1.0f - alpha) + alpha * ar;   // white background composite
        out[3 * r + 1] = (1.0f - alpha) + alpha * ag;
        out[3 * r + 2] = (1.0f - alpha) + alpha * ab;
        out[3 * n_rays + r]     = ad;                   // depth
        out[4 * n_rays + r]     = alpha;                // alpha
        out[5 * n_rays + r]     = (alpha > 0.0f) ? 1.0f : 0.0f;  // hit
    }
}

extern "C" void kernel_launch(void* const* d_in, const int* in_sizes, int n_in,
                              void* d_out, int out_size, void* d_ws, size_t ws_size,
                              hipStream_t stream) {
    const float* color   = (const float*)d_in[0];
    const float* density = (const float*)d_in[1];
    const float* deltas  = (const float*)d_in[2];
    const float* depths  = (const float*)d_in[3];
    const int*   ridx    = (const int*)d_in[4];
    float* out = (float*)d_out;

    const int n_samples = in_sizes[1];      // density element count == N
    const int n_rays    = out_size / 6;     // rgb(3R) + depth(R) + alpha(R) + hit(R)

    const int waves_per_block = 256 / 64;
    const int blocks = (n_rays + waves_per_block - 1) / waves_per_block;
    render_kernel<<<blocks, 256, 0, stream>>>(color, density, deltas, depths,
                                              ridx, out, n_samples, n_rays);
}

// Round 2
// 51.624 us; speedup vs baseline: 1.7789x; 1.7789x over previous
//
#include <hip/hip_runtime.h>

// Packed volume-render (NeRF ray compositing).
// Pass 1: stream ridx, write per-ray segment start offsets into d_ws (R+1 ints).
// Pass 2: one wave (64 lanes) per ray:
//   - read [start,end) from the precomputed table (no binary search)
//   - stream the segment in 64-sample chunks (coalesced loads)
//   - wave-scan (shfl_up) of tau for the exclusive segmented cumsum
//   - accumulate w, w*color, w*depth; final wave reduce; lane 0 writes outputs.

__global__ __launch_bounds__(256) void starts_kernel(
    const int* __restrict__ ridx, int* __restrict__ starts,
    int n_samples, int n_rays)
{
    const int t = blockIdx.x * blockDim.x + threadIdx.x;
    const int i0 = t * 4;
    if (i0 >= n_samples) return;

    int prev = (i0 == 0) ? -1 : ridx[i0 - 1];
    const int nj = min(4, n_samples - i0);
    if (nj == 4) {
        const int4 v = *reinterpret_cast<const int4*>(ridx + i0);
        const int cur[4] = {v.x, v.y, v.z, v.w};
        #pragma unroll
        for (int j = 0; j < 4; ++j) {
            const int c = cur[j];
            for (int r = prev + 1; r <= c; ++r) starts[r] = i0 + j;
            prev = c;
        }
    } else {
        for (int j = 0; j < nj; ++j) {
            const int c = ridx[i0 + j];
            for (int r = prev + 1; r <= c; ++r) starts[r] = i0 + j;
            prev = c;
        }
    }
    if (i0 + 4 >= n_samples) {       // last thread closes the table
        for (int r = prev + 1; r <= n_rays; ++r) starts[r] = n_samples;
    }
}

template <bool USE_STARTS>
__global__ __launch_bounds__(256) void render_kernel(
    const float* __restrict__ color,    // [N,3]
    const float* __restrict__ density,  // [N,1]
    const float* __restrict__ deltas,   // [N,1]
    const float* __restrict__ depths,   // [N,1]
    const int*   __restrict__ ridx,     // [N] sorted (fallback path only)
    const int*   __restrict__ starts,   // [R+1]
    float*       __restrict__ out,      // rgb[3R] | depth[R] | alpha[R] | hit[R]
    int n_samples, int n_rays)
{
    const int wave = (int)((blockIdx.x * blockDim.x + threadIdx.x) >> 6);
    const int lane = (int)(threadIdx.x & 63);
    if (wave >= n_rays) return;
    const int r = wave;

    int start, end;
    if (USE_STARTS) {
        start = starts[r];
        end   = starts[r + 1];
    } else {
        // lower_bound(ridx, r) on lane 0, lower_bound(ridx, r+1) elsewhere
        int target = r + (lane ? 1 : 0);
        int lo = 0, hi = n_samples;
        while (lo < hi) {
            int mid = (lo + hi) >> 1;
            if (ridx[mid] < target) lo = mid + 1; else hi = mid;
        }
        start = __shfl(lo, 0);
        end   = __shfl(lo, 1);
    }

    float carry = 0.0f;                 // cumulative tau from previous chunks
    float aw = 0.0f, ar = 0.0f, ag = 0.0f, ab = 0.0f, ad = 0.0f;

    for (int base = start; base < end; base += 64) {
        const int i = base + lane;
        const bool valid = (i < end);
        float tau = 0.0f, c0 = 0.0f, c1 = 0.0f, c2 = 0.0f, dp = 0.0f;
        if (valid) {
            tau = density[i] * deltas[i];
            c0  = color[3 * i + 0];
            c1  = color[3 * i + 1];
            c2  = color[3 * i + 2];
            dp  = depths[i];
        }
        // inclusive wave scan of tau
        float x = tau;
        #pragma unroll
        for (int o = 1; o < 64; o <<= 1) {
            float y = __shfl_up(x, o);
            if (lane >= o) x += y;
        }
        const float excl = carry + (x - tau);       // exclusive segmented cumsum
        const float w = __expf(-excl) * (1.0f - __expf(-tau));
        aw += w;
        ar += w * c0;
        ag += w * c1;
        ab += w * c2;
        ad += w * dp;
        carry += __shfl(x, 63);                     // chunk total (invalid lanes add 0)
    }

    // wave reduction of the 5 accumulators
    #pragma unroll
    for (int o = 32; o > 0; o >>= 1) {
        aw += __shfl_down(aw, o);
        ar += __shfl_down(ar, o);
        ag += __shfl_down(ag, o);
        ab += __shfl_down(ab, o);
        ad += __shfl_down(ad, o);
    }

    if (lane == 0) {
        const float alpha = aw;
        out[3 * r + 0] = (1.0f - alpha) + alpha * ar;   // white background composite
        out[3 * r + 1] = (1.0f - alpha) + alpha * ag;
        out[3 * r + 2] = (1.0f - alpha) + alpha * ab;
        out[3 * n_rays + r]     = ad;                   // depth
        out[4 * n_rays + r]     = alpha;                // alpha
        out[5 * n_rays + r]     = (alpha > 0.0f) ? 1.0f : 0.0f;  // hit
    }
}

extern "C" void kernel_launch(void* const* d_in, const int* in_sizes, int n_in,
                              void* d_out, int out_size, void* d_ws, size_t ws_size,
                              hipStream_t stream) {
    const float* color   = (const float*)d_in[0];
    const float* density = (const float*)d_in[1];
    const float* deltas  = (const float*)d_in[2];
    const float* depths  = (const float*)d_in[3];
    const int*   ridx    = (const int*)d_in[4];
    float* out = (float*)d_out;

    const int n_samples = in_sizes[1];      // density element count == N
    const int n_rays    = out_size / 6;     // rgb(3R) + depth(R) + alpha(R) + hit(R)

    const size_t starts_bytes = (size_t)(n_rays + 1) * sizeof(int);
    const int waves_per_block = 256 / 64;
    const int rblocks = (n_rays + waves_per_block - 1) / waves_per_block;

    if (ws_size >= starts_bytes) {
        int* starts = (int*)d_ws;
        const int nthreads = (n_samples + 3) / 4;
        const int sblocks = (nthreads + 255) / 256;
        starts_kernel<<<sblocks, 256, 0, stream>>>(ridx, starts, n_samples, n_rays);
        render_kernel<true><<<rblocks, 256, 0, stream>>>(
            color, density, deltas, depths, ridx, starts, out, n_samples, n_rays);
    } else {
        render_kernel<false><<<rblocks, 256, 0, stream>>>(
            color, density, deltas, depths, ridx, (const int*)nullptr, out,
            n_samples, n_rays);
    }
}